// Round 6
// baseline (351.024 us; speedup 1.0000x reference)
//
#include <hip/hip_runtime.h>
#include <math.h>

#define D 128
#define NNODES 10000
#define NEDGES 16384
#define PADR 136   // bf16 row stride for xjb/rootT; 272B rows, 16B-aligned
#define MAXDEG 16

typedef short short8 __attribute__((ext_vector_type(8)));
typedef float floatx4 __attribute__((ext_vector_type(4)));
typedef float f32x16 __attribute__((ext_vector_type(16)));

__device__ __forceinline__ float bf2f(unsigned short u) {
  union { unsigned u; float f; } v; v.u = ((unsigned)u) << 16; return v.f;
}
__device__ __forceinline__ unsigned short f2bf(float f) {
  union { float f; unsigned u; } v; v.f = f;
  return (unsigned short)((v.u + 0x7FFFu + ((v.u >> 16) & 1u)) >> 16);
}
__device__ __forceinline__ float bflo(unsigned u) {
  union { unsigned u; float f; } v; v.u = u << 16; return v.f;
}
__device__ __forceinline__ float bfhi(unsigned u) {
  union { unsigned u; float f; } v; v.u = u & 0xFFFF0000u; return v.f;
}
__device__ __forceinline__ short8 pack8(float4 a, float4 b) {
  short8 r;
  r[0] = (short)f2bf(a.x); r[1] = (short)f2bf(a.y);
  r[2] = (short)f2bf(a.z); r[3] = (short)f2bf(a.w);
  r[4] = (short)f2bf(b.x); r[5] = (short)f2bf(b.y);
  r[6] = (short)f2bf(b.z); r[7] = (short)f2bf(b.w);
  return r;
}

// K12: merged prep + edge kernel. Grid 776:
//   bid <  516 : w2t k-plane transpose -> NEW contiguous layout [k][o][i]
//                (k=bid>>2, o0=(bid&3)*32); bid<40 zero cnt
//   516..519   : rootT transpose (PADR layout, unchanged)
//   bid >= 520 : edge work (e0=(bid-520)*64); w1 self-transposed into LDS.
__global__ __launch_bounds__(256) void k12(
    const float* __restrict__ x, const int* __restrict__ eidx,
    const float* __restrict__ ea,
    const float* __restrict__ w1, const float* __restrict__ b1,
    const float* __restrict__ w2, const float* __restrict__ b2,
    const float* __restrict__ root,
    unsigned short* __restrict__ w2t, unsigned short* __restrict__ rootT,
    unsigned short* __restrict__ hT, unsigned short* __restrict__ xjb,
    int* __restrict__ cnt) {
  __shared__ float L[32][129];            // 16,512 B
  __shared__ unsigned short w1tL[128 * PADR];  // 34,816 B (edge path only)
  const int t = threadIdx.x;
  const int bid = blockIdx.x;

  if (bid < 520) {
    // ---------------- prep path ----------------
    if (bid < 40) { const int gid = bid * 256 + t; if (gid < NNODES) cnt[gid] = 0; }
    const float* __restrict__ src;
    unsigned short* dst;
    int o0, dstride;
    if (bid < 516) {
      const int k = bid >> 2;
      o0 = (bid & 3) * 32;
      src = (k < D) ? (w2 + (long)k * (D * D)) : b2;
      dst = w2t + (long)k * (D * D);   // contiguous [k][o][i], row = 256B
      dstride = D;
    } else {
      o0 = (bid - 516) * 32; src = root; dst = rootT; dstride = PADR;
    }
#pragma unroll
    for (int r = 0; r < 16; ++r) {
      int idx = r * 256 + t;
      int i = idx >> 5, oc = idx & 31;
      L[oc][i] = src[i * D + o0 + oc];
    }
    __syncthreads();
#pragma unroll
    for (int r = 0; r < 8; ++r) {
      int p = r * 256 + t;
      int oc = p >> 6, i2 = (p & 63) * 2;
      unsigned v = (unsigned)f2bf(L[oc][i2]) | ((unsigned)f2bf(L[oc][i2 + 1]) << 16);
      *(unsigned*)(dst + ((o0 + oc) * dstride + i2)) = v;
    }
    return;
  }

  // ---------------- edge path (w1t from LDS) ----------------
  const int e0 = (bid - 520) * 64;
#pragma unroll 4
  for (int r = 0; r < 16; ++r) {
    int idx = r * 256 + t, e = idx >> 6, i2 = (idx & 63) * 2;
    const int s = eidx[e0 + e];
    const float2 v = *(const float2*)(x + (long)s * D + i2);
    unsigned p = (unsigned)f2bf(v.x) | ((unsigned)f2bf(v.y) << 16);
    *(unsigned*)(xjb + ((e0 + e) * PADR + i2)) = p;
  }
  for (int c = 0; c < 4; ++c) {
    const int o0c = c * 32;
#pragma unroll
    for (int r = 0; r < 16; ++r) {
      int idx = r * 256 + t;
      int i = idx >> 5, oc = idx & 31;
      L[oc][i] = w1[i * D + o0c + oc];
    }
    __syncthreads();
#pragma unroll
    for (int r = 0; r < 8; ++r) {
      int p = r * 256 + t;
      int oc = p >> 6, i2 = (p & 63) * 2;
      unsigned v = (unsigned)f2bf(L[oc][i2]) | ((unsigned)f2bf(L[oc][i2 + 1]) << 16);
      *(unsigned*)(w1tL + ((o0c + oc) * PADR + i2)) = v;
    }
    __syncthreads();
  }
  const int lane = t & 63, w = t >> 6, lo = lane & 15, hi = lane >> 4;
  short8 af[4];
#pragma unroll
  for (int ks = 0; ks < 4; ++ks) {
    const float* p0 = ea + (long)(e0 + w * 16 + lo) * D + ks * 32 + hi * 8;
    af[ks] = pack8(*(const float4*)p0, *(const float4*)(p0 + 4));
  }
  floatx4 acc[8];
#pragma unroll
  for (int nt = 0; nt < 8; ++nt) acc[nt] = (floatx4){0.f, 0.f, 0.f, 0.f};
#pragma unroll
  for (int ks = 0; ks < 4; ++ks) {
    const int ib = ks * 32 + hi * 8;
#pragma unroll
    for (int nt = 0; nt < 8; ++nt) {
      const short8 bf_ = *(const short8*)&w1tL[(nt * 16 + lo) * PADR + ib];
      acc[nt] = __builtin_amdgcn_mfma_f32_16x16x32_bf16(af[ks], bf_, acc[nt], 0, 0, 0);
    }
  }
#pragma unroll
  for (int nt = 0; nt < 8; ++nt) {
    const int ko = nt * 16 + lo;
    const float b1v = b1[ko];
    float v0 = fmaxf(acc[nt][0] + b1v, 0.f);
    float v1 = fmaxf(acc[nt][1] + b1v, 0.f);
    float v2 = fmaxf(acc[nt][2] + b1v, 0.f);
    float v3 = fmaxf(acc[nt][3] + b1v, 0.f);
    uint2 pk;
    pk.x = (unsigned)f2bf(v0) | ((unsigned)f2bf(v1) << 16);
    pk.y = (unsigned)f2bf(v2) | ((unsigned)f2bf(v3) << 16);
    *(uint2*)(hT + (ko * NEDGES + e0 + w * 16 + hi * 4)) = pk;
  }
  if (t < 64) hT[128 * NEDGES + e0 + t] = 0x3F80;  // bf16(1.0) ones-row (b2)
}

// K3 v11: 32x32x16 MFMA. Block = 128e x 32o x 64/65 k; grid 1024 = 128eg x
// 4oq x 2kh (exactly 4 blocks/CU, zero tail). Wave = 32e x 32o tile:
//   - 8 chained MFMAs per k-plane (full-rate same-acc chaining, m119)
//   - A-frags (w2t rows, contiguous [k][o][i]) streamed from L2, single
//     buffer with reload-after-issue (7-MFMA ~236cy window > L2 ~220cy)
//   - P ping-pong (PA/PB): finish-fmacs of body k issue under body k+1
//   - regs ~124 -> 4 waves/SIMD under launch_bounds(256,4); LDS 16.6KB
//   - h per lane = ONE scalar (C col = lane&31 = e); hLT linear bf16
__global__ __launch_bounds__(256, 4) void k3_msg(
    const unsigned short* __restrict__ w2t,
    const unsigned short* __restrict__ xjb,
    const unsigned short* __restrict__ hT,
    const int* __restrict__ eidx, int* __restrict__ cnt,
    int* __restrict__ elist,
    unsigned short* __restrict__ msgout) {
  __shared__ unsigned short hLT[65 * 128];  // 16,640 B; linear [kk][e]
  const int t = threadIdx.x;
  const int b = blockIdx.x;
  const int kh = b & 1;
  const int oq = (b >> 1) & 3;      // (oq,kh) fixed per XCD -> w2t slice L2-hot
  const int eg = b >> 3;
  const int e0 = eg * 128;
  const int o0 = oq * 32;
  const int kbase = kh * 64;
  const int kcnt = kh ? 65 : 64;    // kh1 includes k=128 (b2 ones-row)
  const int lane = t & 63, wv = t >> 6;
  const int col = lane & 31;        // = e within wave tile = o-row for A-frag
  const int hi = lane >> 5;         // k-half within frag
  const int we = wv * 32;           // wave e-offset

  // adjacency build (cnt zeroed by k12, prior dispatch)
  if ((b & 7) == 0 && t < 128) {
    const int e = e0 + t;
    const int d = eidx[NEDGES + e];
    const int pos = atomicAdd(&cnt[d], 1);
    if (pos < MAXDEG) elist[d * MAXDEG + pos] = e;
  }

  // stage hLT (linear bf16 copy, no permute)
  for (int idx = t; idx < kcnt * 64; idx += 256) {
    const int kk = idx >> 6, e2 = (idx & 63) * 2;
    *(unsigned*)&hLT[kk * 128 + e2] =
        *(const unsigned*)&hT[(long)(kbase + kk) * NEDGES + e0 + e2];
  }

  // xf: B-frags; lane holds x_j[e = e0+we+col][i = ks*16 + hi*8 .. +8]
  short8 xf[8];
  {
    const unsigned short* xp = xjb + (long)(e0 + we + col) * PADR + hi * 8;
#pragma unroll
    for (int ks = 0; ks < 8; ++ks) xf[ks] = *(const short8*)(xp + ks * 16);
  }
  __syncthreads();  // the only barrier

  const long PLANE = (long)D * D;   // 16384 shorts per k-plane
  const unsigned short* ap = w2t + (long)kbase * PLANE + (o0 + col) * D + hi * 8;
  short8 a[8];
#pragma unroll
  for (int ks = 0; ks < 8; ++ks) a[ks] = *(const short8*)(ap + ks * 16);

  f32x16 PA = (f32x16)0.f, PB = (f32x16)0.f, msg = (f32x16)0.f;
  const unsigned short* hb = hLT + we + col;

  auto chain = [&](f32x16& P, const unsigned short* nb) {
#pragma unroll
    for (int ks = 0; ks < 8; ++ks) {
      P = __builtin_amdgcn_mfma_f32_32x32x16_bf16(a[ks], xf[ks], P, 0, 0, 0);
      a[ks] = *(const short8*)(nb + ks * 16);   // reload-after-issue (next plane)
    }
  };
  auto finish = [&](float h, const f32x16& P) {
#pragma unroll
    for (int r = 0; r < 16; ++r) msg[r] += h * P[r];
  };

  float hA = bf2f(hb[0]);
  const unsigned short* nb = ap + PLANE;   // plane 1
  chain(PA, nb);                           // body 0; a <- plane 1
  int k = 1;
  for (; k + 1 < kcnt; k += 2) {
    nb += PLANE;                           // plane k+1
    const float hBv = bf2f(hb[k * 128]);
    chain(PB, nb);                         // body k; a <- plane k+1
    finish(hA, PA); PA = (f32x16)0.f;
    if (k + 2 < kcnt) nb += PLANE;         // plane k+2 (clamped at end)
    hA = bf2f(hb[(k + 1) * 128]);
    chain(PA, nb);                         // body k+1; a <- plane k+2
    finish(hBv, PB); PB = (f32x16)0.f;
  }
  if (k < kcnt) {                          // kcnt even: one leftover body
    const float hBv = bf2f(hb[k * 128]);
    chain(PB, nb);                         // benign reload of current plane
    finish(hA, PA);
    finish(hBv, PB);
  } else {
    finish(hA, PA);
  }

  // store bf16 half: msgout[kh][e][o]; lane's 16 accs = one e, o-groups of 4
  {
    const long e = e0 + we + col;
    unsigned short* mp = msgout + ((long)kh * NEDGES + e) * D + o0 + hi * 4;
#pragma unroll
    for (int g = 0; g < 4; ++g) {          // o = o0 + 8g + 4hi + (0..3)
      uint2 pk;
      pk.x = (unsigned)f2bf(msg[g * 4 + 0]) | ((unsigned)f2bf(msg[g * 4 + 1]) << 16);
      pk.y = (unsigned)f2bf(msg[g * 4 + 2]) | ((unsigned)f2bf(msg[g * 4 + 3]) << 16);
      *(uint2*)(mp + g * 8) = pk;
    }
  }
}

// K4 = round-4 byte-identical (fused reduce + output). Grid 157.
__global__ __launch_bounds__(256) void k4_out(
    const float* __restrict__ x, const unsigned short* __restrict__ rootT,
    const float* __restrict__ bias, const unsigned short* __restrict__ msg,
    const int* __restrict__ cnt, const int* __restrict__ elist,
    float* __restrict__ out) {
  __shared__ float segL[64 * 132];  // 33,792 B, 16B-aligned rows
  const int t = threadIdx.x;
  const int n0 = blockIdx.x * 64;
  {
    const int ln = t >> 2;
    const int n = n0 + ln;
    const int oq = (t & 3) * 32;
    float a[32];
#pragma unroll
    for (int i = 0; i < 32; ++i) a[i] = 0.f;
    if (n < NNODES) {
      const int deg = min(cnt[n], MAXDEG);
      for (int j = 0; j < deg; ++j) {
        const int e = elist[n * MAXDEG + j];
        const unsigned short* r0 = msg + (long)e * D + oq;
        const unsigned short* r1 = r0 + (long)NEDGES * D;
#pragma unroll
        for (int q = 0; q < 4; ++q) {
          const uint4 u0 = *(const uint4*)(r0 + q * 8);
          const uint4 u1 = *(const uint4*)(r1 + q * 8);
          a[q * 8 + 0] += bflo(u0.x) + bflo(u1.x);
          a[q * 8 + 1] += bfhi(u0.x) + bfhi(u1.x);
          a[q * 8 + 2] += bflo(u0.y) + bflo(u1.y);
          a[q * 8 + 3] += bfhi(u0.y) + bfhi(u1.y);
          a[q * 8 + 4] += bflo(u0.z) + bflo(u1.z);
          a[q * 8 + 5] += bfhi(u0.z) + bfhi(u1.z);
          a[q * 8 + 6] += bflo(u0.w) + bflo(u1.w);
          a[q * 8 + 7] += bfhi(u0.w) + bfhi(u1.w);
        }
      }
    }
#pragma unroll
    for (int q = 0; q < 8; ++q)
      *(float4*)&segL[ln * 132 + oq + q * 4] =
          (float4){a[q * 4], a[q * 4 + 1], a[q * 4 + 2], a[q * 4 + 3]};
  }
  __syncthreads();
  const int lane = t & 63, w = t >> 6, lo = lane & 15, hi = lane >> 4;
  const int nrow = n0 + w * 16 + lo;
  short8 af[4];
#pragma unroll
  for (int ks = 0; ks < 4; ++ks) {
    if (nrow < NNODES) {
      const float* p0 = x + (long)nrow * D + ks * 32 + hi * 8;
      af[ks] = pack8(*(const float4*)p0, *(const float4*)(p0 + 4));
    } else {
      af[ks] = (short8){0, 0, 0, 0, 0, 0, 0, 0};
    }
  }
  floatx4 acc[8];
#pragma unroll
  for (int nt = 0; nt < 8; ++nt) acc[nt] = (floatx4){0.f, 0.f, 0.f, 0.f};
#pragma unroll
  for (int ks = 0; ks < 4; ++ks) {
    const int ib = ks * 32 + hi * 8;
#pragma unroll
    for (int nt = 0; nt < 8; ++nt) {
      const short8 bf_ = *(const short8*)&rootT[(nt * 16 + lo) * PADR + ib];
      acc[nt] = __builtin_amdgcn_mfma_f32_16x16x32_bf16(af[ks], bf_, acc[nt], 0, 0, 0);
    }
  }
  float dinv[4];
#pragma unroll
  for (int r = 0; r < 4; ++r) {
    const int n = n0 + w * 16 + hi * 4 + r;
    dinv[r] = (n < NNODES) ? 1.0f / fmaxf((float)cnt[n], 1.0f) : 0.f;
  }
#pragma unroll
  for (int nt = 0; nt < 8; ++nt) {
    const int co = nt * 16 + lo;
    const float bv = bias[co];
#pragma unroll
    for (int r = 0; r < 4; ++r) {
      const int n = n0 + w * 16 + hi * 4 + r;
      if (n < NNODES) {
        const float aggr = segL[(w * 16 + hi * 4 + r) * 132 + co] * dinv[r];
        const float v = acc[nt][r] + aggr + bv;
        const float ge = 0.5f * v * (1.0f + erff(v * 0.70710678f));
        out[(long)n * D + co] = x[(long)n * D + co] + ge;
      }
    }
  }
}

extern "C" void kernel_launch(void* const* d_in, const int* in_sizes, int n_in,
                              void* d_out, int out_size, void* d_ws, size_t ws_size,
                              hipStream_t stream) {
  (void)in_sizes; (void)n_in; (void)out_size; (void)ws_size;
  const float* x    = (const float*)d_in[0];
  const int*   eidx = (const int*)d_in[1];
  const float* ea   = (const float*)d_in[2];
  const float* w1   = (const float*)d_in[3];
  const float* b1   = (const float*)d_in[4];
  const float* w2   = (const float*)d_in[5];
  const float* b2   = (const float*)d_in[6];
  const float* root = (const float*)d_in[7];
  const float* bias = (const float*)d_in[8];
  float* out = (float*)d_out;
  char* ws = (char*)d_ws;
  // ws layout (bytes):
  //   hT    @ 0          : 129*16384*2     = 4,227,072
  //   xjb   @ 4,227,072  : 16384*136*2     = 4,456,448
  //   w2t   @ 8,683,520  : 129*128*128*2   = 4,227,072 (contiguous [k][o][i])
  //   msg   @13,174,784  : 2*16384*128*2   = 8,388,608
  //   cnt   @21,563,392  : 40,000
  //   elist @21,603,392  : 640,000
  //   rootT @22,243,392  : 34,816          (total 22,278,208)
  unsigned short* hT    = (unsigned short*)(ws + 0);
  unsigned short* xjb   = (unsigned short*)(ws + 4227072);
  unsigned short* w2t   = (unsigned short*)(ws + 8683520);
  unsigned short* msg   = (unsigned short*)(ws + 13174784);
  int*            cnt   = (int*)(ws + 21563392);
  int*            elist = (int*)(ws + 21603392);
  unsigned short* rootT = (unsigned short*)(ws + 22243392);
  hipLaunchKernelGGL(k12, dim3(776), dim3(256), 0, stream,
                     x, eidx, ea, w1, b1, w2, b2, root, w2t, rootT, hT, xjb, cnt);
  hipLaunchKernelGGL(k3_msg, dim3(1024), dim3(256), 0, stream,
                     w2t, xjb, hT, eidx, cnt, elist, msg);
  hipLaunchKernelGGL(k4_out, dim3((NNODES + 63) / 64), dim3(256), 0, stream,
                     x, rootT, bias, msg, cnt, elist, out);
}

// Round 7
// 174.974 us; speedup vs baseline: 2.0061x; 2.0061x over previous
//
#include <hip/hip_runtime.h>
#include <math.h>

#define D 128
#define NNODES 10000
#define NEDGES 16384
#define PADR 136   // bf16 row stride for xjb/rootT; 272B rows, 16B-aligned
#define MAXDEG 16

typedef short short8 __attribute__((ext_vector_type(8)));
typedef float floatx4 __attribute__((ext_vector_type(4)));

__device__ __forceinline__ float bf2f(unsigned short u) {
  union { unsigned u; float f; } v; v.u = ((unsigned)u) << 16; return v.f;
}
__device__ __forceinline__ unsigned short f2bf(float f) {
  union { float f; unsigned u; } v; v.f = f;
  return (unsigned short)((v.u + 0x7FFFu + ((v.u >> 16) & 1u)) >> 16);
}
__device__ __forceinline__ float bflo(unsigned u) {
  union { unsigned u; float f; } v; v.u = u << 16; return v.f;
}
__device__ __forceinline__ float bfhi(unsigned u) {
  union { unsigned u; float f; } v; v.u = u & 0xFFFF0000u; return v.f;
}
__device__ __forceinline__ short8 pack8(float4 a, float4 b) {
  short8 r;
  r[0] = (short)f2bf(a.x); r[1] = (short)f2bf(a.y);
  r[2] = (short)f2bf(a.z); r[3] = (short)f2bf(a.w);
  r[4] = (short)f2bf(b.x); r[5] = (short)f2bf(b.y);
  r[6] = (short)f2bf(b.z); r[7] = (short)f2bf(b.w);
  return r;
}

// K12: merged prep + edge kernel. Grid 776:
//   bid <  516 : w2t k-plane transpose -> MFMA-FRAGMENT layout
//                [k][oq][wg][ks][lane][8]  (lane = lo + 16*hi), so k3's
//                per-wave A-load is ONE coalesced 1KB transaction.
//                (k=bid>>2, oq=bid&3); bid<40 zero cnt
//   516..519   : rootT transpose (PADR layout, unchanged)
//   bid >= 520 : edge work (e0=(bid-520)*64); w1 self-transposed into LDS.
__global__ __launch_bounds__(256) void k12(
    const float* __restrict__ x, const int* __restrict__ eidx,
    const float* __restrict__ ea,
    const float* __restrict__ w1, const float* __restrict__ b1,
    const float* __restrict__ w2, const float* __restrict__ b2,
    const float* __restrict__ root,
    unsigned short* __restrict__ w2t, unsigned short* __restrict__ rootT,
    unsigned short* __restrict__ hT, unsigned short* __restrict__ xjb,
    int* __restrict__ cnt) {
  __shared__ float L[32][129];            // 16,512 B
  __shared__ unsigned short w1tL[128 * PADR];  // 34,816 B (edge path only)
  const int t = threadIdx.x;
  const int bid = blockIdx.x;

  if (bid < 520) {
    // ---------------- prep path ----------------
    if (bid < 40) { const int gid = bid * 256 + t; if (gid < NNODES) cnt[gid] = 0; }
    const float* __restrict__ src;
    int o0;
    if (bid < 516) {
      const int k = bid >> 2;
      o0 = (bid & 3) * 32;
      src = (k < D) ? (w2 + (long)k * (D * D)) : b2;
    } else {
      o0 = (bid - 516) * 32; src = root;
    }
#pragma unroll
    for (int r = 0; r < 16; ++r) {
      int idx = r * 256 + t;
      int i = idx >> 5, oc = idx & 31;
      L[oc][i] = src[i * D + o0 + oc];
    }
    __syncthreads();
#pragma unroll
    for (int r = 0; r < 8; ++r) {
      int p = r * 256 + t;
      int oc = p >> 6, i2 = (p & 63) * 2;
      unsigned v = (unsigned)f2bf(L[oc][i2]) | ((unsigned)f2bf(L[oc][i2 + 1]) << 16);
      if (bid < 516) {
        // fragment layout: elem (o = o0+oc, i = i2) ->
        //   ((((k*4+oq)*2+wg)*4+ks)*512 + (lo+16*hi)*8 + j)
        const long k = bid >> 2, oq = bid & 3;
        const int wg = oc >> 4, lo = oc & 15;
        const int ks = i2 >> 5, hi = (i2 & 31) >> 3, j = i2 & 7;
        const long off = ((((k * 4 + oq) * 2 + wg) * 4 + ks) * 512) +
                         (lo + 16 * hi) * 8 + j;
        *(unsigned*)(w2t + off) = v;   // j even -> pair stays in one 8-chunk
      } else {
        *(unsigned*)(rootT + ((o0 + oc) * PADR + i2)) = v;
      }
    }
    return;
  }

  // ---------------- edge path (w1t from LDS) ----------------
  const int e0 = (bid - 520) * 64;
#pragma unroll 4
  for (int r = 0; r < 16; ++r) {
    int idx = r * 256 + t, e = idx >> 6, i2 = (idx & 63) * 2;
    const int s = eidx[e0 + e];
    const float2 v = *(const float2*)(x + (long)s * D + i2);
    unsigned p = (unsigned)f2bf(v.x) | ((unsigned)f2bf(v.y) << 16);
    *(unsigned*)(xjb + ((e0 + e) * PADR + i2)) = p;
  }
  for (int c = 0; c < 4; ++c) {
    const int o0c = c * 32;
#pragma unroll
    for (int r = 0; r < 16; ++r) {
      int idx = r * 256 + t;
      int i = idx >> 5, oc = idx & 31;
      L[oc][i] = w1[i * D + o0c + oc];
    }
    __syncthreads();
#pragma unroll
    for (int r = 0; r < 8; ++r) {
      int p = r * 256 + t;
      int oc = p >> 6, i2 = (p & 63) * 2;
      unsigned v = (unsigned)f2bf(L[oc][i2]) | ((unsigned)f2bf(L[oc][i2 + 1]) << 16);
      *(unsigned*)(w1tL + ((o0c + oc) * PADR + i2)) = v;
    }
    __syncthreads();
  }
  const int lane = t & 63, w = t >> 6, lo = lane & 15, hi = lane >> 4;
  short8 af[4];
#pragma unroll
  for (int ks = 0; ks < 4; ++ks) {
    const float* p0 = ea + (long)(e0 + w * 16 + lo) * D + ks * 32 + hi * 8;
    af[ks] = pack8(*(const float4*)p0, *(const float4*)(p0 + 4));
  }
  floatx4 acc[8];
#pragma unroll
  for (int nt = 0; nt < 8; ++nt) acc[nt] = (floatx4){0.f, 0.f, 0.f, 0.f};
#pragma unroll
  for (int ks = 0; ks < 4; ++ks) {
    const int ib = ks * 32 + hi * 8;
#pragma unroll
    for (int nt = 0; nt < 8; ++nt) {
      const short8 bf_ = *(const short8*)&w1tL[(nt * 16 + lo) * PADR + ib];
      acc[nt] = __builtin_amdgcn_mfma_f32_16x16x32_bf16(af[ks], bf_, acc[nt], 0, 0, 0);
    }
  }
#pragma unroll
  for (int nt = 0; nt < 8; ++nt) {
    const int ko = nt * 16 + lo;
    const float b1v = b1[ko];
    float v0 = fmaxf(acc[nt][0] + b1v, 0.f);
    float v1 = fmaxf(acc[nt][1] + b1v, 0.f);
    float v2 = fmaxf(acc[nt][2] + b1v, 0.f);
    float v3 = fmaxf(acc[nt][3] + b1v, 0.f);
    uint2 pk;
    pk.x = (unsigned)f2bf(v0) | ((unsigned)f2bf(v1) << 16);
    pk.y = (unsigned)f2bf(v2) | ((unsigned)f2bf(v3) << 16);
    *(uint2*)(hT + (ko * NEDGES + e0 + w * 16 + hi * 4)) = pk;
  }
  if (t < 64) hT[128 * NEDGES + e0 + t] = 0x3F80;  // bf16(1.0) ones-row (b2)
}

// K3 = proven v7 structure (round-4, 81.0us) with ONE delta: A-loads from the
// fragment-packed w2t -> each ldA is a single coalesced 1KB wave transaction
// (was: 64 lanes scattered across 272B-strided rows = ~8x VMEM request fan-out
// + 4x segment overfetch). Loop/LDS/registers/stores byte-identical. No setprio.
__global__ __launch_bounds__(256, 3) void k3_msg(
    const unsigned short* __restrict__ w2t,
    const unsigned short* __restrict__ xjb,
    const unsigned short* __restrict__ hT,
    const int* __restrict__ eidx, int* __restrict__ cnt,
    int* __restrict__ elist,
    unsigned short* __restrict__ msgout) {
  __shared__ float hLT[65 * 128];   // 33,280 B; idx = kk*128 + (e>>6)*64 + (e&15)*4 + ((e>>4)&3)
  const int t = threadIdx.x;
  const int b = blockIdx.x;
  const int kh = b & 1;
  const int oq = (b >> 1) & 3;      // (oq,kh) fixed per XCD -> w2t slice L2-hot
  const int eg = b >> 3;
  const int e0 = eg * 128;
  const int o0 = oq * 32;
  const int kbase = kh * 64;
  const int kcnt = kh ? 65 : 64;    // kh1 includes k=128 (b2 ones-row)
  const int lane = t & 63, wv = t >> 6;
  const int lo = lane & 15, hi = lane >> 4;
  const int we = (wv >> 1) * 64;
  const int wg = wv & 1;            // o-group (wo = wg*16)
  const int wo = wg * 16;

  // adjacency build (cnt zeroed by k12, prior dispatch)
  if ((b & 7) == 0 && t < 128) {
    const int e = e0 + t;
    const int d = eidx[NEDGES + e];
    const int pos = atomicAdd(&cnt[d], 1);
    if (pos < MAXDEG) elist[d * MAXDEG + pos] = e;
  }

  // stage hLT (permuted) from hT; 2 edges per thread-iter
  for (int idx = t; idx < kcnt * 64; idx += 256) {
    const int kk = idx >> 6, e2 = (idx & 63) * 2;
    const unsigned u = *(const unsigned*)&hT[(long)(kbase + kk) * NEDGES + e0 + e2];
    const int ebase = kk * 128;
#pragma unroll
    for (int q = 0; q < 2; ++q) {
      const int e = e2 + q;
      hLT[ebase + ((e >> 6) << 6) + ((e & 15) << 2) + ((e >> 4) & 3)] =
          q ? bfhi(u) : bflo(u);
    }
  }

  // xf from xjb (k-invariant, b128, no conversion)
  short8 xf[4][4];
#pragma unroll
  for (int ne = 0; ne < 4; ++ne)
#pragma unroll
    for (int ks = 0; ks < 4; ++ks)
      xf[ne][ks] = *(const short8*)&xjb[(long)(e0 + we + ne * 16 + lo) * PADR + ks * 32 + hi * 8];
  __syncthreads();  // the only barrier

  // fragment-packed A: frag(k, ks) at ((((k*4+oq)*2+wg)*4+ks)*512 + lane*8
  const long PLANE = (long)D * D;   // 16384 shorts between consecutive k
  const unsigned short* ap =
      w2t + ((((long)kbase * 4 + oq) * 2 + wg) * 4) * 512 + lane * 8;
  const float* hp = hLT + we + lo * 4;
  short8 a0[4], a1[4];
#pragma unroll
  for (int ks = 0; ks < 4; ++ks) a0[ks] = *(const short8*)(ap + ks * 512);
#pragma unroll
  for (int ks = 0; ks < 4; ++ks) a1[ks] = *(const short8*)(ap + PLANE + ks * 512);
  floatx4 msg[4];
#pragma unroll
  for (int ne = 0; ne < 4; ++ne) msg[ne] = (floatx4){0.f, 0.f, 0.f, 0.f};

  auto body = [&](short8* fr, int k) {
    const floatx4 h4 = *(const floatx4*)(hp + k * 128);
    floatx4 P[4];
#pragma unroll
    for (int ne = 0; ne < 4; ++ne) P[ne] = (floatx4){0.f, 0.f, 0.f, 0.f};
#pragma unroll
    for (int ks = 0; ks < 4; ++ks)
#pragma unroll
      for (int ne = 0; ne < 4; ++ne)
        P[ne] = __builtin_amdgcn_mfma_f32_16x16x32_bf16(fr[ks], xf[ne][ks], P[ne], 0, 0, 0);
#pragma unroll
    for (int ne = 0; ne < 4; ++ne)
#pragma unroll
      for (int r = 0; r < 4; ++r) msg[ne][r] += h4[ne] * P[ne][r];
  };

  const int kpairs = kcnt >> 1;
  for (int j = 0; j < kpairs; ++j) {
    const int k = j * 2;
    body(a0, k);
    {
      const int kp = (k + 2 < kcnt) ? k + 2 : 0;
#pragma unroll
      for (int ks = 0; ks < 4; ++ks)
        a0[ks] = *(const short8*)(ap + (long)kp * PLANE + ks * 512);
    }
    body(a1, k + 1);
    {
      const int kp = (k + 3 < kcnt) ? k + 3 : 0;
#pragma unroll
      for (int ks = 0; ks < 4; ++ks)
        a1[ks] = *(const short8*)(ap + (long)kp * PLANE + ks * 512);
    }
  }
  if (kcnt & 1) body(a0, kcnt - 1);

  // store bf16 half: msgout[kh][e][o]
#pragma unroll
  for (int ne = 0; ne < 4; ++ne) {
    const long e = e0 + we + ne * 16 + lo;
    uint2 pk;
    pk.x = (unsigned)f2bf(msg[ne][0]) | ((unsigned)f2bf(msg[ne][1]) << 16);
    pk.y = (unsigned)f2bf(msg[ne][2]) | ((unsigned)f2bf(msg[ne][3]) << 16);
    *(uint2*)(msgout + ((long)kh * NEDGES + e) * D + o0 + wo + hi * 4) = pk;
  }
}

// K4 = round-4 byte-identical (fused reduce + output). Grid 157.
__global__ __launch_bounds__(256) void k4_out(
    const float* __restrict__ x, const unsigned short* __restrict__ rootT,
    const float* __restrict__ bias, const unsigned short* __restrict__ msg,
    const int* __restrict__ cnt, const int* __restrict__ elist,
    float* __restrict__ out) {
  __shared__ float segL[64 * 132];  // 33,792 B, 16B-aligned rows
  const int t = threadIdx.x;
  const int n0 = blockIdx.x * 64;
  {
    const int ln = t >> 2;
    const int n = n0 + ln;
    const int oq = (t & 3) * 32;
    float a[32];
#pragma unroll
    for (int i = 0; i < 32; ++i) a[i] = 0.f;
    if (n < NNODES) {
      const int deg = min(cnt[n], MAXDEG);
      for (int j = 0; j < deg; ++j) {
        const int e = elist[n * MAXDEG + j];
        const unsigned short* r0 = msg + (long)e * D + oq;
        const unsigned short* r1 = r0 + (long)NEDGES * D;
#pragma unroll
        for (int q = 0; q < 4; ++q) {
          const uint4 u0 = *(const uint4*)(r0 + q * 8);
          const uint4 u1 = *(const uint4*)(r1 + q * 8);
          a[q * 8 + 0] += bflo(u0.x) + bflo(u1.x);
          a[q * 8 + 1] += bfhi(u0.x) + bfhi(u1.x);
          a[q * 8 + 2] += bflo(u0.y) + bflo(u1.y);
          a[q * 8 + 3] += bfhi(u0.y) + bfhi(u1.y);
          a[q * 8 + 4] += bflo(u0.z) + bflo(u1.z);
          a[q * 8 + 5] += bfhi(u0.z) + bfhi(u1.z);
          a[q * 8 + 6] += bflo(u0.w) + bflo(u1.w);
          a[q * 8 + 7] += bfhi(u0.w) + bfhi(u1.w);
        }
      }
    }
#pragma unroll
    for (int q = 0; q < 8; ++q)
      *(float4*)&segL[ln * 132 + oq + q * 4] =
          (float4){a[q * 4], a[q * 4 + 1], a[q * 4 + 2], a[q * 4 + 3]};
  }
  __syncthreads();
  const int lane = t & 63, w = t >> 6, lo = lane & 15, hi = lane >> 4;
  const int nrow = n0 + w * 16 + lo;
  short8 af[4];
#pragma unroll
  for (int ks = 0; ks < 4; ++ks) {
    if (nrow < NNODES) {
      const float* p0 = x + (long)nrow * D + ks * 32 + hi * 8;
      af[ks] = pack8(*(const float4*)p0, *(const float4*)(p0 + 4));
    } else {
      af[ks] = (short8){0, 0, 0, 0, 0, 0, 0, 0};
    }
  }
  floatx4 acc[8];
#pragma unroll
  for (int nt = 0; nt < 8; ++nt) acc[nt] = (floatx4){0.f, 0.f, 0.f, 0.f};
#pragma unroll
  for (int ks = 0; ks < 4; ++ks) {
    const int ib = ks * 32 + hi * 8;
#pragma unroll
    for (int nt = 0; nt < 8; ++nt) {
      const short8 bf_ = *(const short8*)&rootT[(nt * 16 + lo) * PADR + ib];
      acc[nt] = __builtin_amdgcn_mfma_f32_16x16x32_bf16(af[ks], bf_, acc[nt], 0, 0, 0);
    }
  }
  float dinv[4];
#pragma unroll
  for (int r = 0; r < 4; ++r) {
    const int n = n0 + w * 16 + hi * 4 + r;
    dinv[r] = (n < NNODES) ? 1.0f / fmaxf((float)cnt[n], 1.0f) : 0.f;
  }
#pragma unroll
  for (int nt = 0; nt < 8; ++nt) {
    const int co = nt * 16 + lo;
    const float bv = bias[co];
#pragma unroll
    for (int r = 0; r < 4; ++r) {
      const int n = n0 + w * 16 + hi * 4 + r;
      if (n < NNODES) {
        const float aggr = segL[(w * 16 + hi * 4 + r) * 132 + co] * dinv[r];
        const float v = acc[nt][r] + aggr + bv;
        const float ge = 0.5f * v * (1.0f + erff(v * 0.70710678f));
        out[(long)n * D + co] = x[(long)n * D + co] + ge;
      }
    }
  }
}

extern "C" void kernel_launch(void* const* d_in, const int* in_sizes, int n_in,
                              void* d_out, int out_size, void* d_ws, size_t ws_size,
                              hipStream_t stream) {
  (void)in_sizes; (void)n_in; (void)out_size; (void)ws_size;
  const float* x    = (const float*)d_in[0];
  const int*   eidx = (const int*)d_in[1];
  const float* ea   = (const float*)d_in[2];
  const float* w1   = (const float*)d_in[3];
  const float* b1   = (const float*)d_in[4];
  const float* w2   = (const float*)d_in[5];
  const float* b2   = (const float*)d_in[6];
  const float* root = (const float*)d_in[7];
  const float* bias = (const float*)d_in[8];
  float* out = (float*)d_out;
  char* ws = (char*)d_ws;
  // ws layout (bytes):
  //   hT    @ 0          : 129*16384*2     = 4,227,072
  //   xjb   @ 4,227,072  : 16384*136*2     = 4,456,448
  //   w2t   @ 8,683,520  : 129*16384*2     = 4,227,072 (fragment layout)
  //   msg   @13,174,784  : 2*16384*128*2   = 8,388,608
  //   cnt   @21,563,392  : 40,000
  //   elist @21,603,392  : 640,000
  //   rootT @22,243,392  : 34,816          (total 22,278,208)
  unsigned short* hT    = (unsigned short*)(ws + 0);
  unsigned short* xjb   = (unsigned short*)(ws + 4227072);
  unsigned short* w2t   = (unsigned short*)(ws + 8683520);
  unsigned short* msg   = (unsigned short*)(ws + 13174784);
  int*            cnt   = (int*)(ws + 21563392);
  int*            elist = (int*)(ws + 21603392);
  unsigned short* rootT = (unsigned short*)(ws + 22243392);
  hipLaunchKernelGGL(k12, dim3(776), dim3(256), 0, stream,
                     x, eidx, ea, w1, b1, w2, b2, root, w2t, rootT, hT, xjb, cnt);
  hipLaunchKernelGGL(k3_msg, dim3(1024), dim3(256), 0, stream,
                     w2t, xjb, hT, eidx, cnt, elist, msg);
  hipLaunchKernelGGL(k4_out, dim3((NNODES + 63) / 64), dim3(256), 0, stream,
                     x, rootT, bias, msg, cnt, elist, out);
}

// Round 8
// 166.587 us; speedup vs baseline: 2.1071x; 1.0503x over previous
//
#include <hip/hip_runtime.h>
#include <math.h>

#define D 128
#define NNODES 10000
#define NEDGES 16384
#define PADR 136   // bf16 row stride for xjb/rootT; 272B rows, 16B-aligned
#define MAXDEG 16

typedef short short8 __attribute__((ext_vector_type(8)));
typedef float floatx4 __attribute__((ext_vector_type(4)));

__device__ __forceinline__ float bf2f(unsigned short u) {
  union { unsigned u; float f; } v; v.u = ((unsigned)u) << 16; return v.f;
}
__device__ __forceinline__ unsigned short f2bf(float f) {
  union { float f; unsigned u; } v; v.f = f;
  return (unsigned short)((v.u + 0x7FFFu + ((v.u >> 16) & 1u)) >> 16);
}
__device__ __forceinline__ float bflo(unsigned u) {
  union { unsigned u; float f; } v; v.u = u << 16; return v.f;
}
__device__ __forceinline__ float bfhi(unsigned u) {
  union { unsigned u; float f; } v; v.u = u & 0xFFFF0000u; return v.f;
}
__device__ __forceinline__ short8 pack8(float4 a, float4 b) {
  short8 r;
  r[0] = (short)f2bf(a.x); r[1] = (short)f2bf(a.y);
  r[2] = (short)f2bf(a.z); r[3] = (short)f2bf(a.w);
  r[4] = (short)f2bf(b.x); r[5] = (short)f2bf(b.y);
  r[6] = (short)f2bf(b.z); r[7] = (short)f2bf(b.w);
  return r;
}

// K12: merged prep + edge kernel. Grid 1032:
//   bid <  516 : w2t k-plane transpose -> MFMA-FRAGMENT layout
//                [k][oq][wg][ks][lane][8]; bid<40 zero cnt
//   516..519   : rootT transpose (PADR layout)
//   bid >= 520 : edge work, now 512 blocks x 32 edges (was 256x64) for 2x
//                gather TLP; per wave: 16 edges x 64 k-cols (kh-half).
__global__ __launch_bounds__(256) void k12(
    const float* __restrict__ x, const int* __restrict__ eidx,
    const float* __restrict__ ea,
    const float* __restrict__ w1, const float* __restrict__ b1,
    const float* __restrict__ w2, const float* __restrict__ b2,
    const float* __restrict__ root,
    unsigned short* __restrict__ w2t, unsigned short* __restrict__ rootT,
    unsigned short* __restrict__ hT, unsigned short* __restrict__ xjb,
    int* __restrict__ cnt) {
  __shared__ float L[32][129];            // 16,512 B
  __shared__ unsigned short w1tL[128 * PADR];  // 34,816 B (edge path only)
  const int t = threadIdx.x;
  const int bid = blockIdx.x;

  if (bid < 520) {
    // ---------------- prep path ----------------
    if (bid < 40) { const int gid = bid * 256 + t; if (gid < NNODES) cnt[gid] = 0; }
    const float* __restrict__ src;
    int o0;
    if (bid < 516) {
      const int k = bid >> 2;
      o0 = (bid & 3) * 32;
      src = (k < D) ? (w2 + (long)k * (D * D)) : b2;
    } else {
      o0 = (bid - 516) * 32; src = root;
    }
#pragma unroll
    for (int r = 0; r < 16; ++r) {
      int idx = r * 256 + t;
      int i = idx >> 5, oc = idx & 31;
      L[oc][i] = src[i * D + o0 + oc];
    }
    __syncthreads();
#pragma unroll
    for (int r = 0; r < 8; ++r) {
      int p = r * 256 + t;
      int oc = p >> 6, i2 = (p & 63) * 2;
      unsigned v = (unsigned)f2bf(L[oc][i2]) | ((unsigned)f2bf(L[oc][i2 + 1]) << 16);
      if (bid < 516) {
        const long k = bid >> 2, oq = bid & 3;
        const int wg = oc >> 4, lo = oc & 15;
        const int ks = i2 >> 5, hi = (i2 & 31) >> 3, j = i2 & 7;
        const long off = ((((k * 4 + oq) * 2 + wg) * 4 + ks) * 512) +
                         (lo + 16 * hi) * 8 + j;
        *(unsigned*)(w2t + off) = v;
      } else {
        *(unsigned*)(rootT + ((o0 + oc) * PADR + i2)) = v;
      }
    }
    return;
  }

  // ---------------- edge path: 32 edges/block, w1t from LDS ----------------
  const int e0 = (bid - 520) * 32;
#pragma unroll 4
  for (int r = 0; r < 8; ++r) {
    int idx = r * 256 + t, e = idx >> 6, i2 = (idx & 63) * 2;
    const int s = eidx[e0 + e];
    const float2 v = *(const float2*)(x + (long)s * D + i2);
    unsigned p = (unsigned)f2bf(v.x) | ((unsigned)f2bf(v.y) << 16);
    *(unsigned*)(xjb + ((e0 + e) * PADR + i2)) = p;
  }
  for (int c = 0; c < 4; ++c) {
    const int o0c = c * 32;
#pragma unroll
    for (int r = 0; r < 16; ++r) {
      int idx = r * 256 + t;
      int i = idx >> 5, oc = idx & 31;
      L[oc][i] = w1[i * D + o0c + oc];
    }
    __syncthreads();
#pragma unroll
    for (int r = 0; r < 8; ++r) {
      int p = r * 256 + t;
      int oc = p >> 6, i2 = (p & 63) * 2;
      unsigned v = (unsigned)f2bf(L[oc][i2]) | ((unsigned)f2bf(L[oc][i2 + 1]) << 16);
      *(unsigned*)(w1tL + ((o0c + oc) * PADR + i2)) = v;
    }
    __syncthreads();
  }
  const int lane = t & 63, w = t >> 6, lo = lane & 15, hi = lane >> 4;
  const int e16 = (w & 1) * 16;     // wave's 16-edge group
  const int kh = (w >> 1) * 64;     // wave's k-half
  short8 af[4];
#pragma unroll
  for (int ks = 0; ks < 4; ++ks) {
    const float* p0 = ea + (long)(e0 + e16 + lo) * D + ks * 32 + hi * 8;
    af[ks] = pack8(*(const float4*)p0, *(const float4*)(p0 + 4));
  }
  floatx4 acc[4];
#pragma unroll
  for (int nt = 0; nt < 4; ++nt) acc[nt] = (floatx4){0.f, 0.f, 0.f, 0.f};
#pragma unroll
  for (int ks = 0; ks < 4; ++ks) {
    const int ib = ks * 32 + hi * 8;
#pragma unroll
    for (int nt = 0; nt < 4; ++nt) {
      const short8 bf_ = *(const short8*)&w1tL[(kh + nt * 16 + lo) * PADR + ib];
      acc[nt] = __builtin_amdgcn_mfma_f32_16x16x32_bf16(af[ks], bf_, acc[nt], 0, 0, 0);
    }
  }
#pragma unroll
  for (int nt = 0; nt < 4; ++nt) {
    const int ko = kh + nt * 16 + lo;
    const float b1v = b1[ko];
    float v0 = fmaxf(acc[nt][0] + b1v, 0.f);
    float v1 = fmaxf(acc[nt][1] + b1v, 0.f);
    float v2 = fmaxf(acc[nt][2] + b1v, 0.f);
    float v3 = fmaxf(acc[nt][3] + b1v, 0.f);
    uint2 pk;
    pk.x = (unsigned)f2bf(v0) | ((unsigned)f2bf(v1) << 16);
    pk.y = (unsigned)f2bf(v2) | ((unsigned)f2bf(v3) << 16);
    *(uint2*)(hT + (ko * NEDGES + e0 + e16 + hi * 4)) = pk;
  }
  if (t < 32) hT[128 * NEDGES + e0 + t] = 0x3F80;  // bf16(1.0) ones-row (b2)
}

// K3 = round-7 byte-identical (proven 72.3us, 958 TF). Fragment-packed A,
// v7 2-buffer k-loop, permuted hLT, adjacency prologue. DO NOT TOUCH.
__global__ __launch_bounds__(256, 3) void k3_msg(
    const unsigned short* __restrict__ w2t,
    const unsigned short* __restrict__ xjb,
    const unsigned short* __restrict__ hT,
    const int* __restrict__ eidx, int* __restrict__ cnt,
    int* __restrict__ elist,
    unsigned short* __restrict__ msgout) {
  __shared__ float hLT[65 * 128];   // 33,280 B; idx = kk*128 + (e>>6)*64 + (e&15)*4 + ((e>>4)&3)
  const int t = threadIdx.x;
  const int b = blockIdx.x;
  const int kh = b & 1;
  const int oq = (b >> 1) & 3;      // (oq,kh) fixed per XCD -> w2t slice L2-hot
  const int eg = b >> 3;
  const int e0 = eg * 128;
  const int o0 = oq * 32;
  const int kbase = kh * 64;
  const int kcnt = kh ? 65 : 64;    // kh1 includes k=128 (b2 ones-row)
  const int lane = t & 63, wv = t >> 6;
  const int lo = lane & 15, hi = lane >> 4;
  const int we = (wv >> 1) * 64;
  const int wg = wv & 1;            // o-group (wo = wg*16)
  const int wo = wg * 16;

  // adjacency build (cnt zeroed by k12, prior dispatch)
  if ((b & 7) == 0 && t < 128) {
    const int e = e0 + t;
    const int d = eidx[NEDGES + e];
    const int pos = atomicAdd(&cnt[d], 1);
    if (pos < MAXDEG) elist[d * MAXDEG + pos] = e;
  }

  // stage hLT (permuted) from hT; 2 edges per thread-iter
  for (int idx = t; idx < kcnt * 64; idx += 256) {
    const int kk = idx >> 6, e2 = (idx & 63) * 2;
    const unsigned u = *(const unsigned*)&hT[(long)(kbase + kk) * NEDGES + e0 + e2];
    const int ebase = kk * 128;
#pragma unroll
    for (int q = 0; q < 2; ++q) {
      const int e = e2 + q;
      hLT[ebase + ((e >> 6) << 6) + ((e & 15) << 2) + ((e >> 4) & 3)] =
          q ? bfhi(u) : bflo(u);
    }
  }

  // xf from xjb (k-invariant, b128, no conversion)
  short8 xf[4][4];
#pragma unroll
  for (int ne = 0; ne < 4; ++ne)
#pragma unroll
    for (int ks = 0; ks < 4; ++ks)
      xf[ne][ks] = *(const short8*)&xjb[(long)(e0 + we + ne * 16 + lo) * PADR + ks * 32 + hi * 8];
  __syncthreads();  // the only barrier

  // fragment-packed A: frag(k, ks) at ((((k*4+oq)*2+wg)*4+ks)*512 + lane*8
  const long PLANE = (long)D * D;   // 16384 shorts between consecutive k
  const unsigned short* ap =
      w2t + ((((long)kbase * 4 + oq) * 2 + wg) * 4) * 512 + lane * 8;
  const float* hp = hLT + we + lo * 4;
  short8 a0[4], a1[4];
#pragma unroll
  for (int ks = 0; ks < 4; ++ks) a0[ks] = *(const short8*)(ap + ks * 512);
#pragma unroll
  for (int ks = 0; ks < 4; ++ks) a1[ks] = *(const short8*)(ap + PLANE + ks * 512);
  floatx4 msg[4];
#pragma unroll
  for (int ne = 0; ne < 4; ++ne) msg[ne] = (floatx4){0.f, 0.f, 0.f, 0.f};

  auto body = [&](short8* fr, int k) {
    const floatx4 h4 = *(const floatx4*)(hp + k * 128);
    floatx4 P[4];
#pragma unroll
    for (int ne = 0; ne < 4; ++ne) P[ne] = (floatx4){0.f, 0.f, 0.f, 0.f};
#pragma unroll
    for (int ks = 0; ks < 4; ++ks)
#pragma unroll
      for (int ne = 0; ne < 4; ++ne)
        P[ne] = __builtin_amdgcn_mfma_f32_16x16x32_bf16(fr[ks], xf[ne][ks], P[ne], 0, 0, 0);
#pragma unroll
    for (int ne = 0; ne < 4; ++ne)
#pragma unroll
      for (int r = 0; r < 4; ++r) msg[ne][r] += h4[ne] * P[ne][r];
  };

  const int kpairs = kcnt >> 1;
  for (int j = 0; j < kpairs; ++j) {
    const int k = j * 2;
    body(a0, k);
    {
      const int kp = (k + 2 < kcnt) ? k + 2 : 0;
#pragma unroll
      for (int ks = 0; ks < 4; ++ks)
        a0[ks] = *(const short8*)(ap + (long)kp * PLANE + ks * 512);
    }
    body(a1, k + 1);
    {
      const int kp = (k + 3 < kcnt) ? k + 3 : 0;
#pragma unroll
      for (int ks = 0; ks < 4; ++ks)
        a1[ks] = *(const short8*)(ap + (long)kp * PLANE + ks * 512);
    }
  }
  if (kcnt & 1) body(a0, kcnt - 1);

  // store bf16 half: msgout[kh][e][o]
#pragma unroll
  for (int ne = 0; ne < 4; ++ne) {
    const long e = e0 + we + ne * 16 + lo;
    uint2 pk;
    pk.x = (unsigned)f2bf(msg[ne][0]) | ((unsigned)f2bf(msg[ne][1]) << 16);
    pk.y = (unsigned)f2bf(msg[ne][2]) | ((unsigned)f2bf(msg[ne][3]) << 16);
    *(uint2*)(msgout + ((long)kh * NEDGES + e) * D + o0 + wo + hi * 4) = pk;
  }
}

// K4: 625 blocks x 16 nodes (was 157x64 = 0.6 blocks/CU, latency-starved).
// Phase A: 16 threads/node x 8 o gather-sum. Phase B: 4 waves share the
// 16-node A-fragment; each wave owns a 32-o slice (nt loop 2).
__global__ __launch_bounds__(256) void k4_out(
    const float* __restrict__ x, const unsigned short* __restrict__ rootT,
    const float* __restrict__ bias, const unsigned short* __restrict__ msg,
    const int* __restrict__ cnt, const int* __restrict__ elist,
    float* __restrict__ out) {
  __shared__ float segL[16 * 132];  // 8,448 B
  const int t = threadIdx.x;
  const int n0 = blockIdx.x * 16;
  // phase A: gather-sum msg rows per node (16 threads/node x 8 o)
  {
    const int ln = t >> 4;
    const int n = n0 + ln;
    const int os = (t & 15) * 8;
    float a[8];
#pragma unroll
    for (int i = 0; i < 8; ++i) a[i] = 0.f;
    if (n < NNODES) {
      const int deg = min(cnt[n], MAXDEG);
      for (int j = 0; j < deg; ++j) {
        const int e = elist[n * MAXDEG + j];
        const unsigned short* r0 = msg + (long)e * D + os;
        const unsigned short* r1 = r0 + (long)NEDGES * D;
        const uint4 u0 = *(const uint4*)r0;
        const uint4 u1 = *(const uint4*)r1;
        a[0] += bflo(u0.x) + bflo(u1.x);
        a[1] += bfhi(u0.x) + bfhi(u1.x);
        a[2] += bflo(u0.y) + bflo(u1.y);
        a[3] += bfhi(u0.y) + bfhi(u1.y);
        a[4] += bflo(u0.z) + bflo(u1.z);
        a[5] += bfhi(u0.z) + bfhi(u1.z);
        a[6] += bflo(u0.w) + bflo(u1.w);
        a[7] += bfhi(u0.w) + bfhi(u1.w);
      }
    }
    *(float4*)&segL[ln * 132 + os] = (float4){a[0], a[1], a[2], a[3]};
    *(float4*)&segL[ln * 132 + os + 4] = (float4){a[4], a[5], a[6], a[7]};
  }
  __syncthreads();
  // phase B: x@root MFMA; wave w owns o-slice w*32..w*32+32
  const int lane = t & 63, w = t >> 6, lo = lane & 15, hi = lane >> 4;
  const int nrow = n0 + lo;
  short8 af[4];
#pragma unroll
  for (int ks = 0; ks < 4; ++ks) {
    if (nrow < NNODES) {
      const float* p0 = x + (long)nrow * D + ks * 32 + hi * 8;
      af[ks] = pack8(*(const float4*)p0, *(const float4*)(p0 + 4));
    } else {
      af[ks] = (short8){0, 0, 0, 0, 0, 0, 0, 0};
    }
  }
  floatx4 acc[2];
#pragma unroll
  for (int nt = 0; nt < 2; ++nt) acc[nt] = (floatx4){0.f, 0.f, 0.f, 0.f};
#pragma unroll
  for (int ks = 0; ks < 4; ++ks) {
    const int ib = ks * 32 + hi * 8;
#pragma unroll
    for (int nt = 0; nt < 2; ++nt) {
      const short8 bf_ = *(const short8*)&rootT[(w * 32 + nt * 16 + lo) * PADR + ib];
      acc[nt] = __builtin_amdgcn_mfma_f32_16x16x32_bf16(af[ks], bf_, acc[nt], 0, 0, 0);
    }
  }
  float dinv[4];
#pragma unroll
  for (int r = 0; r < 4; ++r) {
    const int n = n0 + hi * 4 + r;
    dinv[r] = (n < NNODES) ? 1.0f / fmaxf((float)cnt[n], 1.0f) : 0.f;
  }
#pragma unroll
  for (int nt = 0; nt < 2; ++nt) {
    const int co = w * 32 + nt * 16 + lo;
    const float bv = bias[co];
#pragma unroll
    for (int r = 0; r < 4; ++r) {
      const int n = n0 + hi * 4 + r;
      if (n < NNODES) {
        const float aggr = segL[(hi * 4 + r) * 132 + co] * dinv[r];
        const float v = acc[nt][r] + aggr + bv;
        const float ge = 0.5f * v * (1.0f + erff(v * 0.70710678f));
        out[(long)n * D + co] = x[(long)n * D + co] + ge;
      }
    }
  }
}

extern "C" void kernel_launch(void* const* d_in, const int* in_sizes, int n_in,
                              void* d_out, int out_size, void* d_ws, size_t ws_size,
                              hipStream_t stream) {
  (void)in_sizes; (void)n_in; (void)out_size; (void)ws_size;
  const float* x    = (const float*)d_in[0];
  const int*   eidx = (const int*)d_in[1];
  const float* ea   = (const float*)d_in[2];
  const float* w1   = (const float*)d_in[3];
  const float* b1   = (const float*)d_in[4];
  const float* w2   = (const float*)d_in[5];
  const float* b2   = (const float*)d_in[6];
  const float* root = (const float*)d_in[7];
  const float* bias = (const float*)d_in[8];
  float* out = (float*)d_out;
  char* ws = (char*)d_ws;
  // ws layout (bytes):
  //   hT    @ 0          : 129*16384*2     = 4,227,072
  //   xjb   @ 4,227,072  : 16384*136*2     = 4,456,448
  //   w2t   @ 8,683,520  : 129*16384*2     = 4,227,072 (fragment layout)
  //   msg   @13,174,784  : 2*16384*128*2   = 8,388,608
  //   cnt   @21,563,392  : 40,000
  //   elist @21,603,392  : 640,000
  //   rootT @22,243,392  : 34,816          (total 22,278,208)
  unsigned short* hT    = (unsigned short*)(ws + 0);
  unsigned short* xjb   = (unsigned short*)(ws + 4227072);
  unsigned short* w2t   = (unsigned short*)(ws + 8683520);
  unsigned short* msg   = (unsigned short*)(ws + 13174784);
  int*            cnt   = (int*)(ws + 21563392);
  int*            elist = (int*)(ws + 21603392);
  unsigned short* rootT = (unsigned short*)(ws + 22243392);
  hipLaunchKernelGGL(k12, dim3(1032), dim3(256), 0, stream,
                     x, eidx, ea, w1, b1, w2, b2, root, w2t, rootT, hT, xjb, cnt);
  hipLaunchKernelGGL(k3_msg, dim3(1024), dim3(256), 0, stream,
                     w2t, xjb, hT, eidx, cnt, elist, msg);
  hipLaunchKernelGGL(k4_out, dim3((NNODES + 15) / 16), dim3(256), 0, stream,
                     x, rootT, bias, msg, cnt, elist, out);
}